// Round 1
// baseline (1272.915 us; speedup 1.0000x reference)
//
#include <hip/hip_runtime.h>

// Shapes (fixed by the reference)
static constexpr int Bc = 8;     // batch
static constexpr int Nn = 2048;  // main graph nodes
static constexpr int Np = 1024;  // second graph nodes

// ---------------------------------------------------------------------------
// Z1 = concat of 9 layer-1 x@W blocks: cols 0-95 = x_n@W_l1a[0..2],
// cols 96+32i = feats[i]@W_l1b[i]. (bias added after A-multiply.)
// ---------------------------------------------------------------------------
__global__ __launch_bounds__(256) void build_z1_kernel(
    const float* __restrict__ x_n,
    const float* __restrict__ f0, const float* __restrict__ f1,
    const float* __restrict__ f2, const float* __restrict__ f3,
    const float* __restrict__ f4, const float* __restrict__ f5,
    const float* __restrict__ W_l1a, const float* __restrict__ W_l1b,
    float* __restrict__ Z1)
{
  int idx = blockIdx.x * 256 + threadIdx.x;
  const int total = Bc * Nn * 288;
  if (idx >= total) return;
  int c = idx % 288;
  int bn = idx / 288;
  int g = c >> 5, h = c & 31;
  float s = 0.f;
  if (g < 3) {
    const float* x = x_n + (long long)bn * 6;
    const float* W = W_l1a + g * 192 + h;   // W_l1a[g][k][h]
    #pragma unroll
    for (int k = 0; k < 6; k++) s = fmaf(x[k], W[k * 32], s);
  } else {
    const float* fp;
    switch (g) { case 3: fp = f0; break; case 4: fp = f1; break;
                 case 5: fp = f2; break; case 6: fp = f3; break;
                 case 7: fp = f4; break; default: fp = f5; }
    const float* x = fp + (long long)bn * 3;
    const float* W = W_l1b + (g - 3) * 96 + h;  // W_l1b[g-3][k][h]
    #pragma unroll
    for (int k = 0; k < 3; k++) s = fmaf(x[k], W[k * 32], s);
  }
  Z1[idx] = s;
}

// Zp = x_p @ W_l1a[3]  -> (B, Np, 32)
__global__ __launch_bounds__(256) void build_zp_kernel(
    const float* __restrict__ x_p, const float* __restrict__ W_l1a,
    float* __restrict__ Zp)
{
  int idx = blockIdx.x * 256 + threadIdx.x;
  const int total = Bc * Np * 32;
  if (idx >= total) return;
  int h = idx & 31;
  int bn = idx >> 5;
  const float* x = x_p + (long long)bn * 6;
  const float* W = W_l1a + 576 + h;  // W_l1a[3][k][h]
  float s = 0.f;
  #pragma unroll
  for (int k = 0; k < 6; k++) s = fmaf(x[k], W[k * 32], s);
  Zp[idx] = s;
}

// bias288: layer-1 concat bias; biasg: layer-2 A_n-group bias (pairs 0,4..9,10)
__global__ void build_bias_kernel(const float* __restrict__ b_l1a,
                                  const float* __restrict__ b_l1b,
                                  const float* __restrict__ b_l2,
                                  float* __restrict__ bias288,
                                  float* __restrict__ biasg)
{
  int t = blockIdx.x * blockDim.x + threadIdx.x;
  if (t < 288) {
    int g = t >> 5, h = t & 31;
    bias288[t] = (g < 3) ? b_l1a[g * 32 + h] : b_l1b[(g - 3) * 32 + h];
  } else if (t < 288 + 256) {
    int c = t - 288;
    int g = c >> 5, h = c & 31;
    const int wsel[8] = {0, 4, 5, 6, 7, 8, 9, 10};
    biasg[c] = b_l2[wsel[g] * 32 + h];
  }
}

// ---------------------------------------------------------------------------
// Z2: layer-2 inputs times W_l2, 352 cols:
//   [0..255]  A_n group:  x11*W0 | xb0*W4 .. xb5*W9 | x14*W10
//   [256..287] x12*W1 (A_n_ts)  [288..319] x12*W2 (A_n_cs)  [320..351] x13*W3 (A_s)
// x14[b,n,h] = pooled[b, n//64]  (constant over h) -> pooled * colsum(W10)
// ---------------------------------------------------------------------------
__global__ __launch_bounds__(256) void build_z2_kernel(
    const float* __restrict__ Y1, const float* __restrict__ pooled,
    const float* __restrict__ W_l2, float* __restrict__ Z2)
{
  int idx = blockIdx.x * 256 + threadIdx.x;
  const int total = Bc * Nn * 352;
  if (idx >= total) return;
  int c = idx % 352;
  int bn = idx / 352;
  int z = c >> 5, h = c & 31;
  const int inoff[11] = {0, 96, 128, 160, 192, 224, 256, -1, 32, 32, 64};
  const int wsel[11]  = {0, 4, 5, 6, 7, 8, 9, 10, 1, 2, 3};
  const float* W = W_l2 + wsel[z] * 1024 + h;  // W_l2[w][k][h]
  float s = 0.f;
  if (z == 7) {
    int b = bn >> 11;
    int n = bn & 2047;
    float pv = pooled[b * 32 + (n >> 6)];
    float wsum = 0.f;
    #pragma unroll
    for (int k = 0; k < 32; k++) wsum += W[k * 32];
    s = pv * wsum;
  } else {
    const float* x = Y1 + (long long)bn * 288 + inoff[z];
    #pragma unroll
    for (int k = 0; k < 32; k++) s = fmaf(x[k], W[k * 32], s);
  }
  Z2[idx] = s;
}

// ---------------------------------------------------------------------------
// Tiled fp32 GEMM: out = relu(A @ B + bias)  (full output)  or
// colsum: out[c] += sum_rows relu(...)  (atomicAdd, layer-2 pooling).
// FUSE3: blockIdx.x selects one of 3 adjacency matrices (ts/cs/s convs),
// each a 32-col problem at B/bias/out offset 32*which.
// Thread layout: 16 (m) x 16 (n) threads, TMxTN micro-tile each.
// A staged transposed in LDS (As[k][m], +4 pad) for float4 fragment reads.
// ---------------------------------------------------------------------------
template<int BM, int BN, int BK, int TM, int TN, bool COLSUM, bool FUSE3>
__global__ __launch_bounds__(256) void gemm_kernel(
    const float* __restrict__ A0, const float* __restrict__ A1,
    const float* __restrict__ A2, long long strideA,
    const float* __restrict__ B0, long long strideB, int ldb,
    const float* __restrict__ bias0,
    float* __restrict__ out0, long long strideOut, int ldout,
    int M, int K, int C)
{
  static_assert((BM / TM) == 16 && (BN / TN) == 16, "16x16 thread grid");
  static_assert((BM * BK) % 1024 == 0 && (BK * BN) % 1024 == 0, "");
  constexpr int LDA = BM + 4;  // pad keeps float4 alignment, breaks pow2 stride
  __shared__ float As[BK][LDA];
  __shared__ float Bs[BK][BN];
  constexpr int RR = COLSUM ? 16 : 1;
  constexpr int RC = COLSUM ? BN : 1;
  __shared__ float Red[RR][RC];

  const int tid = threadIdx.x;
  const int tn = tid & 15;
  const int tm = tid >> 4;
  const int batch = blockIdx.z;

  const float* A = A0;
  const float* Bm = B0;
  const float* bias = bias0;
  float* out = out0;
  int n0 = blockIdx.x * BN;
  if constexpr (FUSE3) {
    int which = blockIdx.x;
    if (which == 1) A = A1; else if (which == 2) A = A2;
    Bm += 32 * which;
    bias += 32 * which;
    out += 32 * which;
    n0 = 0;
  }
  A   += (long long)batch * strideA;
  Bm  += (long long)batch * strideB;
  out += (long long)batch * strideOut;
  const int m0 = blockIdx.y * BM;

  float acc[TM][TN];
  #pragma unroll
  for (int i = 0; i < TM; i++)
    #pragma unroll
    for (int j = 0; j < TN; j++) acc[i][j] = 0.f;

  constexpr int AF4 = (BM * BK) / 1024;
  constexpr int BF4 = (BK * BN) / 1024;

  for (int k0 = 0; k0 < K; k0 += BK) {
    #pragma unroll
    for (int f = 0; f < AF4; f++) {
      int flat = (f * 256 + tid) * 4;
      int r  = flat / BK;
      int kc = flat % BK;
      const float4 v = *(const float4*)(A + (long long)(m0 + r) * K + (k0 + kc));
      As[kc + 0][r] = v.x; As[kc + 1][r] = v.y;
      As[kc + 2][r] = v.z; As[kc + 3][r] = v.w;
    }
    #pragma unroll
    for (int f = 0; f < BF4; f++) {
      int flat = (f * 256 + tid) * 4;
      int kr = flat / BN;
      int nc = flat % BN;
      int c = n0 + nc;
      float4 v;
      const float* brow = Bm + (long long)(k0 + kr) * ldb;
      if (c + 3 < C) {
        v = *(const float4*)(brow + c);
      } else {
        v.x = (c + 0 < C) ? brow[c + 0] : 0.f;
        v.y = (c + 1 < C) ? brow[c + 1] : 0.f;
        v.z = (c + 2 < C) ? brow[c + 2] : 0.f;
        v.w = (c + 3 < C) ? brow[c + 3] : 0.f;
      }
      *(float4*)&Bs[kr][nc] = v;
    }
    __syncthreads();
    #pragma unroll
    for (int kk = 0; kk < BK; kk++) {
      float a[TM], bb[TN];
      #pragma unroll
      for (int i = 0; i < TM; i += 4) {
        const float4 v = *(const float4*)&As[kk][tm * TM + i];
        a[i] = v.x; a[i + 1] = v.y; a[i + 2] = v.z; a[i + 3] = v.w;
      }
      if constexpr (TN == 4) {
        const float4 v = *(const float4*)&Bs[kk][tn * TN];
        bb[0] = v.x; bb[1] = v.y; bb[2] = v.z; bb[3] = v.w;
      } else {
        const float2 v = *(const float2*)&Bs[kk][tn * TN];
        bb[0] = v.x; bb[1] = v.y;
      }
      #pragma unroll
      for (int i = 0; i < TM; i++)
        #pragma unroll
        for (int j = 0; j < TN; j++)
          acc[i][j] = fmaf(a[i], bb[j], acc[i][j]);
    }
    __syncthreads();
  }

  if constexpr (!COLSUM) {
    #pragma unroll
    for (int i = 0; i < TM; i++) {
      int row = m0 + tm * TM + i;
      #pragma unroll
      for (int j = 0; j < TN; j++) {
        int c = n0 + tn * TN + j;
        if (c < C) {
          float v = acc[i][j] + bias[c];
          out[(long long)row * ldout + c] = fmaxf(v, 0.f);
        }
      }
    }
  } else {
    // relu + partial column-sum over this block's BM rows, then atomicAdd.
    float ps[TN];
    #pragma unroll
    for (int j = 0; j < TN; j++) {
      int c = n0 + tn * TN + j;
      float bv = (c < C) ? bias[c] : 0.f;
      float s = 0.f;
      #pragma unroll
      for (int i = 0; i < TM; i++) s += fmaxf(acc[i][j] + bv, 0.f);
      ps[j] = s;
    }
    #pragma unroll
    for (int j = 0; j < TN; j++) Red[tm][tn * TN + j] = ps[j];
    __syncthreads();
    #pragma unroll
    for (int s = 8; s >= 1; s >>= 1) {
      if (tm < s) {
        #pragma unroll
        for (int j = 0; j < TN; j++)
          Red[tm][tn * TN + j] += Red[tm + s][tn * TN + j];
      }
      __syncthreads();
    }
    if (tm == 0) {
      #pragma unroll
      for (int j = 0; j < TN; j++) {
        int c = n0 + tn * TN + j;
        if (c < C) atomicAdd(&out[c], Red[0][tn * TN + j]);
      }
    }
  }
}

// ---------------------------------------------------------------------------
// Final head: reorder pooled2 (storage order) -> pair order, then
// 352->128 relu, 128->128 relu, 128->1. One block, 128 threads.
// ---------------------------------------------------------------------------
__global__ __launch_bounds__(128) void final_mlp_kernel(
    const float* __restrict__ p2,
    const float* __restrict__ Wd1, const float* __restrict__ bd1,
    const float* __restrict__ Wd2, const float* __restrict__ bd2,
    const float* __restrict__ Wo,  const float* __restrict__ bo,
    float* __restrict__ outp)
{
  __shared__ float q [Bc][352];
  __shared__ float q1[Bc][128];
  __shared__ float q2[Bc][128];
  int t = threadIdx.x;
  // pair p lives at storage offset map[p]
  const int map[11] = {0, 256, 288, 320, 32, 64, 96, 128, 160, 192, 224};
  for (int i = t; i < Bc * 352; i += 128) {
    int b = i / 352, c = i % 352;
    int p = c >> 5, h = c & 31;
    q[b][c] = p2[b * 352 + map[p] + h];
  }
  __syncthreads();
  for (int b = 0; b < Bc; b++) {
    float s = bd1[t];
    for (int i = 0; i < 352; i++) s = fmaf(q[b][i], Wd1[i * 128 + t], s);
    q1[b][t] = fmaxf(s, 0.f);
  }
  __syncthreads();
  for (int b = 0; b < Bc; b++) {
    float s = bd2[t];
    for (int i = 0; i < 128; i++) s = fmaf(q1[b][i], Wd2[i * 128 + t], s);
    q2[b][t] = fmaxf(s, 0.f);
  }
  __syncthreads();
  if (t < Bc) {
    float s = bo[0];
    for (int i = 0; i < 128; i++) s = fmaf(q2[t][i], Wo[i], s);
    outp[t] = s;
  }
}

// ---------------------------------------------------------------------------
extern "C" void kernel_launch(void* const* d_in, const int* in_sizes, int n_in,
                              void* d_out, int out_size, void* d_ws, size_t ws_size,
                              hipStream_t stream) {
  (void)in_sizes; (void)n_in; (void)out_size; (void)ws_size;
  const float* x_n   = (const float*)d_in[0];
  const float* A_n   = (const float*)d_in[1];
  const float* A_s   = (const float*)d_in[2];
  const float* A_ts  = (const float*)d_in[3];
  const float* A_cs  = (const float*)d_in[4];
  const float* x_p   = (const float*)d_in[6];
  const float* A_p   = (const float*)d_in[7];
  const float* fg0   = (const float*)d_in[8];
  const float* fg1   = (const float*)d_in[9];
  const float* fg2   = (const float*)d_in[10];
  const float* fg3   = (const float*)d_in[11];
  const float* fg4   = (const float*)d_in[12];
  const float* fg5   = (const float*)d_in[13];
  const float* W_l1a = (const float*)d_in[14];
  const float* b_l1a = (const float*)d_in[15];
  const float* W_l1b = (const float*)d_in[16];
  const float* b_l1b = (const float*)d_in[17];
  const float* W_l2  = (const float*)d_in[18];
  const float* b_l2  = (const float*)d_in[19];
  const float* Wd1   = (const float*)d_in[20];
  const float* bd1   = (const float*)d_in[21];
  const float* Wd2   = (const float*)d_in[22];
  const float* bd2   = (const float*)d_in[23];
  const float* Wo    = (const float*)d_in[24];
  const float* bo    = (const float*)d_in[25];
  float* outp = (float*)d_out;

  // workspace carve-up (floats); total ~62 MB
  float* ws      = (float*)d_ws;
  float* Z1      = ws;                              // 8*2048*288
  float* Y1      = Z1 + (size_t)Bc * Nn * 288;      // 8*2048*288
  float* Z2      = Y1 + (size_t)Bc * Nn * 288;      // 8*2048*352
  float* Zp      = Z2 + (size_t)Bc * Nn * 352;      // 8*1024*32
  float* pooled  = Zp + (size_t)Bc * Np * 32;       // 8*32
  float* p2      = pooled + Bc * 32;                // 8*352
  float* bias288 = p2 + Bc * 352;                   // 288
  float* biasg   = bias288 + 288;                   // 256

  // zero the atomic accumulators (ws is poisoned 0xAA before each call)
  hipMemsetAsync(pooled, 0, (Bc * 32 + Bc * 352) * sizeof(float), stream);

  build_bias_kernel<<<1, 576, 0, stream>>>(b_l1a, b_l1b, b_l2, bias288, biasg);

  {
    int total = Bc * Nn * 288;
    build_z1_kernel<<<(total + 255) / 256, 256, 0, stream>>>(
        x_n, fg0, fg1, fg2, fg3, fg4, fg5, W_l1a, W_l1b, Z1);
  }
  {
    int total = Bc * Np * 32;
    build_zp_kernel<<<(total + 255) / 256, 256, 0, stream>>>(x_p, W_l1a, Zp);
  }

  // layer 1 main: Y1 = relu(A_n @ Z1 + bias288), 288 cols
  gemm_kernel<64, 64, 32, 4, 4, false, false>
      <<<dim3(5, Nn / 64, Bc), 256, 0, stream>>>(
      A_n, nullptr, nullptr, (long long)Nn * Nn,
      Z1, (long long)Nn * 288, 288,
      bias288, Y1, (long long)Nn * 288, 288,
      Nn, Nn, 288);

  // second graph: pooled += colsum(relu(A_p @ Zp + b_l1a[3]))
  gemm_kernel<64, 32, 32, 4, 2, true, false>
      <<<dim3(1, Np / 64, Bc), 256, 0, stream>>>(
      A_p, nullptr, nullptr, (long long)Np * Np,
      Zp, (long long)Np * 32, 32,
      b_l1a + 96, pooled, 32, 0,
      Np, Np, 32);

  {
    int total = Bc * Nn * 352;
    build_z2_kernel<<<(total + 255) / 256, 256, 0, stream>>>(Y1, pooled, W_l2, Z2);
  }

  // layer 2, A_n group (pairs 0,4..9,10): p2[0..255] += colsum(relu(A_n @ Z2 + biasg))
  gemm_kernel<64, 64, 32, 4, 4, true, false>
      <<<dim3(4, Nn / 64, Bc), 256, 0, stream>>>(
      A_n, nullptr, nullptr, (long long)Nn * Nn,
      Z2, (long long)Nn * 352, 352,
      biasg, p2, 352, 0,
      Nn, Nn, 256);

  // layer 2, pairs 1/2/3 with A_n_ts / A_n_cs / A_s (fused via blockIdx.x)
  gemm_kernel<64, 32, 32, 4, 2, true, true>
      <<<dim3(3, Nn / 64, Bc), 256, 0, stream>>>(
      A_ts, A_cs, A_s, (long long)Nn * Nn,
      Z2 + 256, (long long)Nn * 352, 352,
      b_l2 + 32, p2 + 256, 352, 0,
      Nn, Nn, 32);

  final_mlp_kernel<<<1, 128, 0, stream>>>(p2, Wd1, bd1, Wd2, bd2, Wo, bo, outp);
}

// Round 2
// 1067.874 us; speedup vs baseline: 1.1920x; 1.1920x over previous
//
#include <hip/hip_runtime.h>

using f32x4  = __attribute__((ext_vector_type(4))) float;
using bf16x8 = __attribute__((ext_vector_type(8))) __bf16;
using bf16x4 = __attribute__((ext_vector_type(4))) __bf16;

static constexpr int Bc = 8;     // batch
static constexpr int Nn = 2048;  // main graph nodes
static constexpr int Np = 1024;  // second graph nodes

// ---------------------------------------------------------------------------
// Z1^T (b, 320, 2048) bf16: rows 0..287 = layer-1 x@W concat (transposed),
// rows 288..319 zero pad so the BN=64 GEMM needs no N guard.
// ---------------------------------------------------------------------------
__global__ __launch_bounds__(256) void build_z1t_kernel(
    const float* __restrict__ x_n,
    const float* __restrict__ f0, const float* __restrict__ f1,
    const float* __restrict__ f2, const float* __restrict__ f3,
    const float* __restrict__ f4, const float* __restrict__ f5,
    const float* __restrict__ W_l1a, const float* __restrict__ W_l1b,
    __bf16* __restrict__ Z1T)
{
  int idx = blockIdx.x * 256 + threadIdx.x;   // total = 8*320*2048, divisible
  int n = idx & 2047;
  int t = idx >> 11;
  int c = t % 320;
  int b = t / 320;
  int g = c >> 5, h = c & 31;
  long long bn = ((long long)b << 11) | n;
  float s = 0.f;
  if (g < 3) {
    const float* x = x_n + bn * 6;
    const float* W = W_l1a + g * 192 + h;     // W_l1a[g][k][h]
    #pragma unroll
    for (int k = 0; k < 6; k++) s = fmaf(x[k], W[k * 32], s);
  } else if (g < 9) {
    const float* fp;
    switch (g) { case 3: fp = f0; break; case 4: fp = f1; break;
                 case 5: fp = f2; break; case 6: fp = f3; break;
                 case 7: fp = f4; break; default: fp = f5; }
    const float* x = fp + bn * 3;
    const float* W = W_l1b + (g - 3) * 96 + h;
    #pragma unroll
    for (int k = 0; k < 3; k++) s = fmaf(x[k], W[k * 32], s);
  }
  Z1T[idx] = (__bf16)s;
}

// Zp^T (b, 32, 1024) bf16 = (x_p @ W_l1a[3])^T
__global__ __launch_bounds__(256) void build_zpt_kernel(
    const float* __restrict__ x_p, const float* __restrict__ W_l1a,
    __bf16* __restrict__ ZpT)
{
  int idx = blockIdx.x * 256 + threadIdx.x;   // total = 8*32*1024
  int n = idx & 1023;
  int t = idx >> 10;
  int h = t & 31;
  int b = t >> 5;
  const float* x = x_p + ((long long)(b << 10) + n) * 6;
  const float* W = W_l1a + 576 + h;           // W_l1a[3][k][h]
  float s = 0.f;
  #pragma unroll
  for (int k = 0; k < 6; k++) s = fmaf(x[k], W[k * 32], s);
  ZpT[idx] = (__bf16)s;
}

// bias320: layer-1 concat bias (pad 288..319 = 0); biasg: layer-2 A_n group
__global__ void build_bias_kernel(const float* __restrict__ b_l1a,
                                  const float* __restrict__ b_l1b,
                                  const float* __restrict__ b_l2,
                                  float* __restrict__ bias320,
                                  float* __restrict__ biasg)
{
  int t = threadIdx.x;
  if (t < 320) {
    int g = t >> 5, h = t & 31;
    bias320[t] = (g < 3) ? b_l1a[g * 32 + h]
               : (g < 9) ? b_l1b[(g - 3) * 32 + h] : 0.f;
  } else if (t < 320 + 256) {
    int c = t - 320;
    int g = c >> 5, h = c & 31;
    const int wsel[8] = {0, 4, 5, 6, 7, 8, 9, 10};
    biasg[c] = b_l2[wsel[g] * 32 + h];
  }
}

// ---------------------------------------------------------------------------
// Z2^T (b, 352, 2048) bf16. Block = (32-node tile, batch); Y1 tile staged in
// LDS (pitch 289 -> conflict-free column reads). x14 path: pooled[b][n/64]
// is tile-uniform (32-aligned tiles) -> pooled * colsum(W_l2[10]).
// ---------------------------------------------------------------------------
__global__ __launch_bounds__(256) void build_z2t_kernel(
    const float* __restrict__ Y1, const float* __restrict__ pooled,
    const float* __restrict__ W_l2, __bf16* __restrict__ Z2T)
{
  __shared__ float Ys[32][289];
  const int b = blockIdx.y;
  const int n0 = blockIdx.x * 32;
  const int tid = threadIdx.x;
  const float* Yb = Y1 + ((long long)(b << 11) + n0) * 288;
  for (int i = tid; i < 32 * 288; i += 256) {
    int r = i / 288, c = i % 288;
    Ys[r][c] = Yb[i];
  }
  float pv = pooled[b * 32 + (n0 >> 6)];
  __syncthreads();
  int nl = tid & 31, cg = tid >> 5;
  for (int zc = cg; zc < 352; zc += 8) {
    int z = zc >> 5, h = zc & 31;
    constexpr int inoff[11] = {0, 96, 128, 160, 192, 224, 256, 0, 32, 32, 64};
    constexpr int wsel[11]  = {0, 4, 5, 6, 7, 8, 9, 10, 1, 2, 3};
    const float* W = W_l2 + wsel[z] * 1024 + h;   // W_l2[w][k][h]
    float s;
    if (z == 7) {
      float ws = 0.f;
      #pragma unroll
      for (int k = 0; k < 32; k++) ws += W[k * 32];
      s = pv * ws;
    } else {
      const float* yr = &Ys[nl][inoff[z]];
      s = 0.f;
      #pragma unroll
      for (int k = 0; k < 32; k++) s = fmaf(yr[k], W[k * 32], s);
    }
    Z2T[((long long)(b * 352 + zc) << 11) + n0 + nl] = (__bf16)s;
  }
}

// ---------------------------------------------------------------------------
// MFMA bf16 GEMM: out = relu(A @ Z + bias) (full store) or column-sum of it
// (COLSUM, atomicAdd). A fp32 in HBM -> bf16 during LDS staging. Z supplied
// transposed+bf16 (row c contiguous in k) -> pure 16B staging copies.
// BM=128, BK=32 (one MFMA K-step). BN=64: 2x2 waves, wave-tile 64x32.
// BN=32: 4x1 waves, wave-tile 32x32. LDS pitch 40 bf16 (80B, 16B-aligned,
// 2-way-max bank aliasing on b128 fragment reads = free).
// FUSE3: blockIdx.x picks adjacency 0/1/2 with B/bias/out offset 32*which.
// Fragment layouts (m89/m91/m120 verified): A[m=lane&15][k=quad*8+j],
// B[k=quad*8+j][n=lane&15], C/D row=quad*4+reg, col=lane&15.
// ---------------------------------------------------------------------------
template<int BN, bool COLSUM, bool FUSE3>
__global__ __launch_bounds__(256) void mfma_gemm_kernel(
    const float* __restrict__ A0, const float* __restrict__ A1,
    const float* __restrict__ A2, long long strideA,
    const __bf16* __restrict__ BT, long long strideB, int Kld,
    const float* __restrict__ bias,
    float* __restrict__ out, long long strideOut, int ldout, int Ccap,
    int K)
{
  constexpr int BM = 128, BK = 32;
  constexpr int WN  = (BN == 64) ? 2 : 1;   // waves across n
  constexpr int WMS = BM / (4 / WN);        // wave m-span: 64 / 32
  constexpr int MI  = WMS / 16;             // m-tiles per wave: 4 / 2
  constexpr int NJ  = (BN / WN) / 16;       // n-tiles per wave: 2
  constexpr int PITCH = BK + 8;             // 40 bf16 = 80 B

  __shared__ __bf16 As[BM][PITCH];
  __shared__ __bf16 Bs[BN][PITCH];

  const int tid  = threadIdx.x;
  const int lane = tid & 63;
  const int quad = lane >> 4;
  const int lr   = lane & 15;
  const int wave = tid >> 6;
  const int wm   = (wave / WN) * WMS;
  const int wn   = (wave % WN) * (BN / WN);
  const int batch = blockIdx.z;
  const int m0    = blockIdx.y * BM;

  const float* A = A0;
  int coln0;
  if constexpr (FUSE3) {
    int which = blockIdx.x;
    if (which == 1) A = A1; else if (which == 2) A = A2;
    coln0 = which * 32;
  } else {
    coln0 = blockIdx.x * BN;
  }
  A += (long long)batch * strideA;
  const __bf16* Bp = BT + (long long)batch * strideB + (long long)coln0 * Kld;
  out += (long long)batch * strideOut;

  f32x4 acc[MI][NJ];
  #pragma unroll
  for (int i = 0; i < MI; i++)
    #pragma unroll
    for (int j = 0; j < NJ; j++)
      #pragma unroll
      for (int r = 0; r < 4; r++) acc[i][j][r] = 0.f;

  for (int k0 = 0; k0 < K; k0 += BK) {
    // stage A: 128x32 fp32 -> bf16. 1024 float4s, 4 per thread.
    #pragma unroll
    for (int f = 0; f < 4; f++) {
      int flat = f * 256 + tid;
      int r = flat >> 3, c4 = flat & 7;
      const float4 v = *(const float4*)(A + (long long)(m0 + r) * K + k0 + c4 * 4);
      bf16x4 w;
      w[0] = (__bf16)v.x; w[1] = (__bf16)v.y;
      w[2] = (__bf16)v.z; w[3] = (__bf16)v.w;
      *(bf16x4*)&As[r][c4 * 4] = w;
    }
    // stage B: BNx32 bf16, 16B per thread
    if (tid < BN * 4) {
      int row = tid >> 2, seg = tid & 3;
      *(uint4*)&Bs[row][seg * 8] =
          *(const uint4*)(Bp + (long long)row * Kld + k0 + seg * 8);
    }
    __syncthreads();

    bf16x8 af[MI], bfr[NJ];
    #pragma unroll
    for (int i = 0; i < MI; i++)
      af[i] = *(const bf16x8*)&As[wm + i * 16 + lr][quad * 8];
    #pragma unroll
    for (int j = 0; j < NJ; j++)
      bfr[j] = *(const bf16x8*)&Bs[wn + j * 16 + lr][quad * 8];
    #pragma unroll
    for (int i = 0; i < MI; i++)
      #pragma unroll
      for (int j = 0; j < NJ; j++)
        acc[i][j] = __builtin_amdgcn_mfma_f32_16x16x32_bf16(
            af[i], bfr[j], acc[i][j], 0, 0, 0);
    __syncthreads();
  }

  if constexpr (!COLSUM) {
    #pragma unroll
    for (int i = 0; i < MI; i++)
      #pragma unroll
      for (int j = 0; j < NJ; j++) {
        int col = coln0 + wn + j * 16 + lr;
        if (col < Ccap) {
          float bv = bias[col];
          #pragma unroll
          for (int r = 0; r < 4; r++) {
            int row = m0 + wm + i * 16 + quad * 4 + r;
            out[(long long)row * ldout + col] = fmaxf(acc[i][j][r] + bv, 0.f);
          }
        }
      }
  } else {
    #pragma unroll
    for (int j = 0; j < NJ; j++) {
      int col = coln0 + wn + j * 16 + lr;
      float bv = bias[col];
      float s = 0.f;
      #pragma unroll
      for (int i = 0; i < MI; i++)
        #pragma unroll
        for (int r = 0; r < 4; r++)
          s += fmaxf(acc[i][j][r] + bv, 0.f);
      s += __shfl_xor(s, 16);
      s += __shfl_xor(s, 32);
      if (quad == 0) atomicAdd(&out[col], s);
    }
  }
}

// ---------------------------------------------------------------------------
// Final head: reorder pooled2 (storage order) -> pair order, then
// 352->128 relu, 128->128 relu, 128->1. One block, 128 threads.
// ---------------------------------------------------------------------------
__global__ __launch_bounds__(128) void final_mlp_kernel(
    const float* __restrict__ p2,
    const float* __restrict__ Wd1, const float* __restrict__ bd1,
    const float* __restrict__ Wd2, const float* __restrict__ bd2,
    const float* __restrict__ Wo,  const float* __restrict__ bo,
    float* __restrict__ outp)
{
  __shared__ float q [Bc][352];
  __shared__ float q1[Bc][128];
  __shared__ float q2[Bc][128];
  int t = threadIdx.x;
  const int map[11] = {0, 256, 288, 320, 32, 64, 96, 128, 160, 192, 224};
  for (int i = t; i < Bc * 352; i += 128) {
    int b = i / 352, c = i % 352;
    int p = c >> 5, h = c & 31;
    q[b][c] = p2[b * 352 + map[p] + h];
  }
  __syncthreads();
  for (int b = 0; b < Bc; b++) {
    float s = bd1[t];
    for (int i = 0; i < 352; i++) s = fmaf(q[b][i], Wd1[i * 128 + t], s);
    q1[b][t] = fmaxf(s, 0.f);
  }
  __syncthreads();
  for (int b = 0; b < Bc; b++) {
    float s = bd2[t];
    for (int i = 0; i < 128; i++) s = fmaf(q1[b][i], Wd2[i * 128 + t], s);
    q2[b][t] = fmaxf(s, 0.f);
  }
  __syncthreads();
  if (t < Bc) {
    float s = bo[0];
    for (int i = 0; i < 128; i++) s = fmaf(q2[t][i], Wo[i], s);
    outp[t] = s;
  }
}

// ---------------------------------------------------------------------------
extern "C" void kernel_launch(void* const* d_in, const int* in_sizes, int n_in,
                              void* d_out, int out_size, void* d_ws, size_t ws_size,
                              hipStream_t stream) {
  (void)in_sizes; (void)n_in; (void)out_size; (void)ws_size;
  const float* x_n   = (const float*)d_in[0];
  const float* A_n   = (const float*)d_in[1];
  const float* A_s   = (const float*)d_in[2];
  const float* A_ts  = (const float*)d_in[3];
  const float* A_cs  = (const float*)d_in[4];
  const float* x_p   = (const float*)d_in[6];
  const float* A_p   = (const float*)d_in[7];
  const float* fg0   = (const float*)d_in[8];
  const float* fg1   = (const float*)d_in[9];
  const float* fg2   = (const float*)d_in[10];
  const float* fg3   = (const float*)d_in[11];
  const float* fg4   = (const float*)d_in[12];
  const float* fg5   = (const float*)d_in[13];
  const float* W_l1a = (const float*)d_in[14];
  const float* b_l1a = (const float*)d_in[15];
  const float* W_l1b = (const float*)d_in[16];
  const float* b_l1b = (const float*)d_in[17];
  const float* W_l2  = (const float*)d_in[18];
  const float* b_l2  = (const float*)d_in[19];
  const float* Wd1   = (const float*)d_in[20];
  const float* bd1   = (const float*)d_in[21];
  const float* Wd2   = (const float*)d_in[22];
  const float* bd2   = (const float*)d_in[23];
  const float* Wo    = (const float*)d_in[24];
  const float* bo    = (const float*)d_in[25];
  float* outp = (float*)d_out;

  // workspace carve-up (~42 MB)
  __bf16* Z1T = (__bf16*)d_ws;                      // 8*320*2048
  __bf16* Z2T = Z1T + (size_t)Bc * 320 * Nn;        // 8*352*2048
  __bf16* ZpT = Z2T + (size_t)Bc * 352 * Nn;        // 8*32*1024
  float*  Y1  = (float*)(ZpT + (size_t)Bc * 32 * Np);  // 8*2048*288 fp32
  float* pooled  = Y1 + (size_t)Bc * Nn * 288;      // 8*32
  float* p2      = pooled + Bc * 32;                // 8*352
  float* bias320 = p2 + Bc * 352;                   // 320
  float* biasg   = bias320 + 320;                   // 256

  hipMemsetAsync(pooled, 0, (Bc * 32 + Bc * 352) * sizeof(float), stream);

  build_bias_kernel<<<1, 576, 0, stream>>>(b_l1a, b_l1b, b_l2, bias320, biasg);
  build_z1t_kernel<<<(Bc * 320 * Nn) / 256, 256, 0, stream>>>(
      x_n, fg0, fg1, fg2, fg3, fg4, fg5, W_l1a, W_l1b, Z1T);
  build_zpt_kernel<<<(Bc * 32 * Np) / 256, 256, 0, stream>>>(x_p, W_l1a, ZpT);

  // layer 1 main: Y1 = relu(A_n @ Z1 + bias), 288 real cols (320 padded)
  mfma_gemm_kernel<64, false, false><<<dim3(5, Nn / 128, Bc), 256, 0, stream>>>(
      A_n, nullptr, nullptr, (long long)Nn * Nn,
      Z1T, (long long)320 * Nn, Nn,
      bias320, Y1, (long long)Nn * 288, 288, 288, Nn);

  // second graph: pooled += colsum(relu(A_p @ Zp + b_l1a[3]))
  mfma_gemm_kernel<32, true, false><<<dim3(1, Np / 128, Bc), 256, 0, stream>>>(
      A_p, nullptr, nullptr, (long long)Np * Np,
      ZpT, (long long)32 * Np, Np,
      b_l1a + 96, pooled, 32, 0, 32, Np);

  build_z2t_kernel<<<dim3(Nn / 32, Bc), 256, 0, stream>>>(Y1, pooled, W_l2, Z2T);

  // layer 2, A_n group (256 cols): p2[0..255] += colsum(relu(A_n @ Z2 + biasg))
  mfma_gemm_kernel<64, true, false><<<dim3(4, Nn / 128, Bc), 256, 0, stream>>>(
      A_n, nullptr, nullptr, (long long)Nn * Nn,
      Z2T, (long long)352 * Nn, Nn,
      biasg, p2, 352, 0, 256, Nn);

  // layer 2, pairs 1/2/3 with A_n_ts / A_n_cs / A_s (fused via blockIdx.x)
  mfma_gemm_kernel<32, true, true><<<dim3(3, Nn / 128, Bc), 256, 0, stream>>>(
      A_ts, A_cs, A_s, (long long)Nn * Nn,
      Z2T + (size_t)256 * Nn, (long long)352 * Nn, Nn,
      b_l2 + 32, p2 + 256, 352, 0, 96, Nn);

  final_mlp_kernel<<<1, 128, 0, stream>>>(p2, Wd1, bd1, Wd2, bd2, Wo, bo, outp);
}

// Round 3
// 963.408 us; speedup vs baseline: 1.3213x; 1.1084x over previous
//
#include <hip/hip_runtime.h>

using f32x4  = __attribute__((ext_vector_type(4))) float;
using bf16x8 = __attribute__((ext_vector_type(8))) __bf16;

static constexpr int Bc = 8;     // batch
static constexpr int Nn = 2048;  // main graph nodes
static constexpr int Np = 1024;  // second graph nodes

// LDS index swizzle: [row][32] bf16, k-segment seg (8 bf16 = 16B) XOR-spread so
// both staging writes and b128 fragment reads are <=2-way bank aliased (free).
__device__ __forceinline__ int sw(int row, int seg) {
  return row * 32 + (((seg ^ (row & 3) ^ ((row >> 2) & 3)) & 3) << 3);
}

// ---------------------------------------------------------------------------
// Z1^T (b, 320, 2048) bf16: rows 0..287 = layer-1 x@W concat (transposed),
// rows 288..319 zero pad.
// ---------------------------------------------------------------------------
__global__ __launch_bounds__(256) void build_z1t_kernel(
    const float* __restrict__ x_n,
    const float* __restrict__ f0, const float* __restrict__ f1,
    const float* __restrict__ f2, const float* __restrict__ f3,
    const float* __restrict__ f4, const float* __restrict__ f5,
    const float* __restrict__ W_l1a, const float* __restrict__ W_l1b,
    __bf16* __restrict__ Z1T)
{
  int idx = blockIdx.x * 256 + threadIdx.x;   // total = 8*320*2048
  int n = idx & 2047;
  int t = idx >> 11;
  int c = t % 320;
  int b = t / 320;
  int g = c >> 5, h = c & 31;
  long long bn = ((long long)b << 11) | n;
  float s = 0.f;
  if (g < 3) {
    const float* x = x_n + bn * 6;
    const float* W = W_l1a + g * 192 + h;     // W_l1a[g][k][h]
    #pragma unroll
    for (int k = 0; k < 6; k++) s = fmaf(x[k], W[k * 32], s);
  } else if (g < 9) {
    const float* fp;
    switch (g) { case 3: fp = f0; break; case 4: fp = f1; break;
                 case 5: fp = f2; break; case 6: fp = f3; break;
                 case 7: fp = f4; break; default: fp = f5; }
    const float* x = fp + bn * 3;
    const float* W = W_l1b + (g - 3) * 96 + h;
    #pragma unroll
    for (int k = 0; k < 3; k++) s = fmaf(x[k], W[k * 32], s);
  }
  Z1T[idx] = (__bf16)s;
}

// Zp^T (b, 32, 1024) bf16 = (x_p @ W_l1a[3])^T
__global__ __launch_bounds__(256) void build_zpt_kernel(
    const float* __restrict__ x_p, const float* __restrict__ W_l1a,
    __bf16* __restrict__ ZpT)
{
  int idx = blockIdx.x * 256 + threadIdx.x;   // total = 8*32*1024
  int n = idx & 1023;
  int t = idx >> 10;
  int h = t & 31;
  int b = t >> 5;
  const float* x = x_p + ((long long)(b << 10) + n) * 6;
  const float* W = W_l1a + 576 + h;           // W_l1a[3][k][h]
  float s = 0.f;
  #pragma unroll
  for (int k = 0; k < 6; k++) s = fmaf(x[k], W[k * 32], s);
  ZpT[idx] = (__bf16)s;
}

// bias320: layer-1 concat bias (pad 288..319 = 0); biasg: layer-2 A_n group
__global__ void build_bias_kernel(const float* __restrict__ b_l1a,
                                  const float* __restrict__ b_l1b,
                                  const float* __restrict__ b_l2,
                                  float* __restrict__ bias320,
                                  float* __restrict__ biasg)
{
  int t = threadIdx.x;
  if (t < 320) {
    int g = t >> 5, h = t & 31;
    bias320[t] = (g < 3) ? b_l1a[g * 32 + h]
               : (g < 9) ? b_l1b[(g - 3) * 32 + h] : 0.f;
  } else if (t < 320 + 256) {
    int c = t - 320;
    int g = c >> 5, h = c & 31;
    const int wsel[8] = {0, 4, 5, 6, 7, 8, 9, 10};
    biasg[c] = b_l2[wsel[g] * 32 + h];
  }
}

// ---------------------------------------------------------------------------
// Z2^T (b, 352, 2048) bf16 from post-relu bf16 Y1.
// ---------------------------------------------------------------------------
__global__ __launch_bounds__(256) void build_z2t_kernel(
    const __bf16* __restrict__ Y1bf, const float* __restrict__ pooled,
    const float* __restrict__ W_l2, __bf16* __restrict__ Z2T)
{
  __shared__ float Ys[32][289];
  const int b = blockIdx.y;
  const int n0 = blockIdx.x * 32;
  const int tid = threadIdx.x;
  const __bf16* Yb = Y1bf + ((size_t)(b * Nn) + n0) * 288;
  for (int i = tid; i < 32 * 36; i += 256) {   // 8-bf16 chunks
    int r = i / 36, c8 = (i % 36) * 8;
    bf16x8 v = *(const bf16x8*)(Yb + (size_t)r * 288 + c8);
    #pragma unroll
    for (int e = 0; e < 8; e++) Ys[r][c8 + e] = (float)v[e];
  }
  float pv = pooled[b * 32 + (n0 >> 6)];
  __syncthreads();
  int nl = tid & 31, cg = tid >> 5;
  for (int zc = cg; zc < 352; zc += 8) {
    int z = zc >> 5, h = zc & 31;
    constexpr int inoff[11] = {0, 96, 128, 160, 192, 224, 256, 0, 32, 32, 64};
    constexpr int wsel[11]  = {0, 4, 5, 6, 7, 8, 9, 10, 1, 2, 3};
    const float* W = W_l2 + wsel[z] * 1024 + h;   // W_l2[w][k][h]
    float s;
    if (z == 7) {
      float wsum = 0.f;
      #pragma unroll
      for (int k = 0; k < 32; k++) wsum += W[k * 32];
      s = pv * wsum;
    } else {
      const float* yr = &Ys[nl][inoff[z]];
      s = 0.f;
      #pragma unroll
      for (int k = 0; k < 32; k++) s = fmaf(yr[k], W[k * 32], s);
    }
    Z2T[((long long)(b * 352 + zc) << 11) + n0 + nl] = (__bf16)s;
  }
}

// ---------------------------------------------------------------------------
// Mega GEMM: full-column blocks (A read ONCE from HBM), BM=64 rows/block,
// 256 threads (4 waves, wave = one 16-row M-tile, all N), double-buffered LDS,
// loads for tile t+1 issued before computing tile t (BW-bound streaming).
// MODE 0: jobs = layer-1 A_n (320 cols, store Y1 bf16 post-relu)
//              + A_p (32 cols, colsum->pooled).        grid = 256+128
// MODE 1: jobs = layer-2 A_n (256 cols, colsum->p2)
//              + A_ts/A_cs/A_s (32 cols each, colsum). grid = 256+768
// No split-K anywhere: relu binds the full K-sum before the column pool.
// ---------------------------------------------------------------------------
template<int BNMAX, int MODE>
__global__ __launch_bounds__(256) void mega_gemm_kernel(
    const float* __restrict__ An,  const float* __restrict__ Aa0,
    const float* __restrict__ Aa1, const float* __restrict__ Aa2,
    const __bf16* __restrict__ BTm, const __bf16* __restrict__ BTa,
    const float* __restrict__ bias_m, const float* __restrict__ bias_a,
    __bf16* __restrict__ Y1bf, float* __restrict__ outm)
{
  constexpr int NJMAX = BNMAX / 16;
  constexpr int NPASS = BNMAX / 64;       // B 16B-chunks per thread (max)
  __shared__ __bf16 As[2][64 * 32];
  __shared__ __bf16 Bs[2][BNMAX * 32];

  const int tid = threadIdx.x;

  const float* Ap; const __bf16* Bp; const float* bias;
  float* outp = nullptr; __bf16* yout = nullptr;
  int Kdim, iters, nj; bool docolsum;
  int b, m0;
  if constexpr (MODE == 0) {
    int id = blockIdx.x;
    if (id < 256) {               // layer-1 main
      b = id >> 5; m0 = (id & 31) * 64;
      Ap = An + ((size_t)b * Nn + m0) * Nn;
      Bp = BTm + (size_t)b * 320 * Nn;
      bias = bias_m; Kdim = Nn; iters = Nn / 32; nj = 20;
      docolsum = false;
      yout = Y1bf + ((size_t)b * Nn + m0) * 288;
    } else {                      // A_p -> pooled
      int id2 = id - 256;
      b = id2 >> 4; m0 = (id2 & 15) * 64;
      Ap = Aa0 + ((size_t)b * Np + m0) * Np;
      Bp = BTa + (size_t)b * 32 * Np;
      bias = bias_a; Kdim = Np; iters = Np / 32; nj = 2;
      docolsum = true; outp = outm + b * 32;
    }
  } else {
    int id = blockIdx.x;
    if (id < 256) {               // layer-2 A_n group (256 cols)
      b = id >> 5; m0 = (id & 31) * 64;
      Ap = An + ((size_t)b * Nn + m0) * Nn;
      Bp = BTm + (size_t)b * 352 * Nn;
      bias = bias_m; nj = 16;
      outp = outm + b * 352;
    } else {                      // ts/cs/s, 32 cols each
      int id2 = id - 256; int which = id2 >> 8; int r = id2 & 255;
      b = r >> 5; m0 = (r & 31) * 64;
      const float* Asel = (which == 0) ? Aa0 : (which == 1) ? Aa1 : Aa2;
      Ap = Asel + ((size_t)b * Nn + m0) * Nn;
      Bp = BTm + (size_t)b * 352 * Nn + (size_t)(256 + 32 * which) * Nn;
      bias = bias_a + 32 * which;
      nj = 2;
      outp = outm + b * 352 + 256 + 32 * which;
    }
    Kdim = Nn; iters = Nn / 32; docolsum = true;
  }

  const int ar = tid >> 2, as = tid & 3;          // A stage: row, k-seg
  const float* Arow = Ap + (size_t)ar * Kdim + as * 8;
  const int nch = nj * 64;                        // active B 16B-chunks

  float4 a0, a1; uint4 bv[NPASS];

  auto issueL = [&](int it) {
    const float* asrc = Arow + it * 32;
    a0 = *(const float4*)(asrc);
    a1 = *(const float4*)(asrc + 4);
    #pragma unroll
    for (int p = 0; p < NPASS; p++) {
      int ch = p * 256 + tid;
      if (ch < nch) {
        int col = ch >> 2, seg = ch & 3;
        bv[p] = *(const uint4*)(Bp + (size_t)col * Kdim + it * 32 + seg * 8);
      }
    }
  };
  auto commitL = [&](int buf) {
    bf16x8 w;
    w[0]=(__bf16)a0.x; w[1]=(__bf16)a0.y; w[2]=(__bf16)a0.z; w[3]=(__bf16)a0.w;
    w[4]=(__bf16)a1.x; w[5]=(__bf16)a1.y; w[6]=(__bf16)a1.z; w[7]=(__bf16)a1.w;
    *(bf16x8*)&As[buf][sw(ar, as)] = w;
    #pragma unroll
    for (int p = 0; p < NPASS; p++) {
      int ch = p * 256 + tid;
      if (ch < nch) {
        int col = ch >> 2, seg = ch & 3;
        *(uint4*)&Bs[buf][sw(col, seg)] = bv[p];
      }
    }
  };

  const int lane = tid & 63, quad = lane >> 4, lr = lane & 15;
  const int wv = tid >> 6;                        // wave = M-tile

  f32x4 acc[NJMAX];
  #pragma unroll
  for (int j = 0; j < NJMAX; j++) acc[j] = (f32x4){0.f, 0.f, 0.f, 0.f};

  issueL(0);
  commitL(0);
  __syncthreads();
  int cur = 0;
  for (int it = 0; it < iters; ++it) {
    const bool more = (it + 1 < iters);
    if (more) issueL(it + 1);                     // loads in flight over compute
    bf16x8 af = *(const bf16x8*)&As[cur][sw(wv * 16 + lr, quad)];
    #pragma unroll
    for (int j = 0; j < NJMAX; j++) {
      if (j < nj) {
        bf16x8 bf = *(const bf16x8*)&Bs[cur][sw(j * 16 + lr, quad)];
        acc[j] = __builtin_amdgcn_mfma_f32_16x16x32_bf16(af, bf, acc[j], 0, 0, 0);
      }
    }
    if (more) commitL(cur ^ 1);
    __syncthreads();
    cur ^= 1;
  }

  if (!docolsum) {
    // Y1 = relu(acc + bias) -> bf16, cols < 288 (rows exact)
    #pragma unroll
    for (int j = 0; j < NJMAX; j++) {
      if (j < 18) {
        int col = j * 16 + lr;
        float bvv = bias[col];
        #pragma unroll
        for (int r = 0; r < 4; r++) {
          int row = wv * 16 + quad * 4 + r;
          yout[(size_t)row * 288 + col] = (__bf16)fmaxf(acc[j][r] + bvv, 0.f);
        }
      }
    }
  } else {
    #pragma unroll
    for (int j = 0; j < NJMAX; j++) {
      if (j < nj) {
        int col = j * 16 + lr;
        float bvv = bias[col];
        float s = 0.f;
        #pragma unroll
        for (int r = 0; r < 4; r++) s += fmaxf(acc[j][r] + bvv, 0.f);
        s += __shfl_xor(s, 16);
        s += __shfl_xor(s, 32);
        if (quad == 0) atomicAdd(&outp[col], s);
      }
    }
  }
}

// ---------------------------------------------------------------------------
// Final head: reorder pooled2 (storage order) -> pair order, then
// 352->128 relu, 128->128 relu, 128->1. One block, 128 threads.
// ---------------------------------------------------------------------------
__global__ __launch_bounds__(128) void final_mlp_kernel(
    const float* __restrict__ p2,
    const float* __restrict__ Wd1, const float* __restrict__ bd1,
    const float* __restrict__ Wd2, const float* __restrict__ bd2,
    const float* __restrict__ Wo,  const float* __restrict__ bo,
    float* __restrict__ outp)
{
  __shared__ float q [Bc][352];
  __shared__ float q1[Bc][128];
  __shared__ float q2[Bc][128];
  int t = threadIdx.x;
  const int map[11] = {0, 256, 288, 320, 32, 64, 96, 128, 160, 192, 224};
  for (int i = t; i < Bc * 352; i += 128) {
    int b = i / 352, c = i % 352;
    int p = c >> 5, h = c & 31;
    q[b][c] = p2[b * 352 + map[p] + h];
  }
  __syncthreads();
  for (int b = 0; b < Bc; b++) {
    float s = bd1[t];
    for (int i = 0; i < 352; i++) s = fmaf(q[b][i], Wd1[i * 128 + t], s);
    q1[b][t] = fmaxf(s, 0.f);
  }
  __syncthreads();
  for (int b = 0; b < Bc; b++) {
    float s = bd2[t];
    for (int i = 0; i < 128; i++) s = fmaf(q1[b][i], Wd2[i * 128 + t], s);
    q2[b][t] = fmaxf(s, 0.f);
  }
  __syncthreads();
  if (t < Bc) {
    float s = bo[0];
    for (int i = 0; i < 128; i++) s = fmaf(q2[t][i], Wo[i], s);
    outp[t] = s;
  }
}

// ---------------------------------------------------------------------------
extern "C" void kernel_launch(void* const* d_in, const int* in_sizes, int n_in,
                              void* d_out, int out_size, void* d_ws, size_t ws_size,
                              hipStream_t stream) {
  (void)in_sizes; (void)n_in; (void)out_size; (void)ws_size;
  const float* x_n   = (const float*)d_in[0];
  const float* A_n   = (const float*)d_in[1];
  const float* A_s   = (const float*)d_in[2];
  const float* A_ts  = (const float*)d_in[3];
  const float* A_cs  = (const float*)d_in[4];
  const float* x_p   = (const float*)d_in[6];
  const float* A_p   = (const float*)d_in[7];
  const float* fg0   = (const float*)d_in[8];
  const float* fg1   = (const float*)d_in[9];
  const float* fg2   = (const float*)d_in[10];
  const float* fg3   = (const float*)d_in[11];
  const float* fg4   = (const float*)d_in[12];
  const float* fg5   = (const float*)d_in[13];
  const float* W_l1a = (const float*)d_in[14];
  const float* b_l1a = (const float*)d_in[15];
  const float* W_l1b = (const float*)d_in[16];
  const float* b_l1b = (const float*)d_in[17];
  const float* W_l2  = (const float*)d_in[18];
  const float* b_l2  = (const float*)d_in[19];
  const float* Wd1   = (const float*)d_in[20];
  const float* bd1   = (const float*)d_in[21];
  const float* Wd2   = (const float*)d_in[22];
  const float* bd2   = (const float*)d_in[23];
  const float* Wo    = (const float*)d_in[24];
  const float* bo    = (const float*)d_in[25];
  float* outp = (float*)d_out;

  // workspace carve-up (~32 MB)
  __bf16* Z1T  = (__bf16*)d_ws;                     // 8*320*2048
  __bf16* Z2T  = Z1T + (size_t)Bc * 320 * Nn;       // 8*352*2048
  __bf16* ZpT  = Z2T + (size_t)Bc * 352 * Nn;       // 8*32*1024
  __bf16* Y1bf = ZpT + (size_t)Bc * 32 * Np;        // 8*2048*288
  float* pooled  = (float*)(Y1bf + (size_t)Bc * Nn * 288);  // 8*32
  float* p2      = pooled + Bc * 32;                // 8*352
  float* bias320 = p2 + Bc * 352;                   // 320
  float* biasg   = bias320 + 320;                   // 256

  hipMemsetAsync(pooled, 0, (Bc * 32 + Bc * 352) * sizeof(float), stream);

  build_bias_kernel<<<1, 576, 0, stream>>>(b_l1a, b_l1b, b_l2, bias320, biasg);
  build_z1t_kernel<<<(Bc * 320 * Nn) / 256, 256, 0, stream>>>(
      x_n, fg0, fg1, fg2, fg3, fg4, fg5, W_l1a, W_l1b, Z1T);
  build_zpt_kernel<<<(Bc * 32 * Np) / 256, 256, 0, stream>>>(x_p, W_l1a, ZpT);

  // phase 1: layer-1 main (Y1) + A_p (pooled), one dispatch, 384 blocks
  mega_gemm_kernel<320, 0><<<384, 256, 0, stream>>>(
      A_n, A_p, nullptr, nullptr, Z1T, ZpT,
      bias320, b_l1a + 96, Y1bf, pooled);

  build_z2t_kernel<<<dim3(Nn / 32, Bc), 256, 0, stream>>>(Y1bf, pooled, W_l2, Z2T);

  // phase 2: layer-2 A_n (256 cols) + ts/cs/s (32 each), one dispatch, 1024 blocks
  mega_gemm_kernel<256, 1><<<1024, 256, 0, stream>>>(
      A_n, A_ts, A_cs, A_s, Z2T, nullptr,
      biasg, b_l2 + 32, nullptr, p2);

  final_mlp_kernel<<<1, 128, 0, stream>>>(p2, Wd1, bd1, Wd2, bd2, Wo, bo, outp);
}